// Round 18
// baseline (317.246 us; speedup 1.0000x reference)
//
#include <hip/hip_runtime.h>
#include <hip/hip_bf16.h>

typedef long long i64;
typedef unsigned int uint;
using u16 = unsigned short;
using f32x4  = __attribute__((ext_vector_type(4))) float;
using bf16x8 = __attribute__((ext_vector_type(8))) short;
using u32x4  = __attribute__((ext_vector_type(4))) uint;
using u16x4  = __attribute__((ext_vector_type(4))) u16;

// 0.125 (attention scaling) * log2(e): applied as an f32 mul on scores so
// softmax uses exp2 directly. Softmax is invariant to the base change.
#define QSCALE 0.18033688011112042f

#if __has_builtin(__builtin_amdgcn_exp2f)
#define EXP2(x) __builtin_amdgcn_exp2f(x)   // raw v_exp_f32 (scores are O(20))
#else
#define EXP2(x) __builtin_exp2f(x)
#endif

__device__ __forceinline__ u16 f2b(float x) {   // f32 -> bf16 RNE
    uint u = __float_as_uint(x);
    return (u16)((u + 0x7FFFu + ((u >> 16) & 1u)) >> 16);
}
__device__ __forceinline__ float b2f(u16 h) {
    return __uint_as_float((uint)h << 16);
}
__device__ __forceinline__ uint cvt_pk_bf16(float lo, float hi) {
    uint r;
    asm("v_cvt_pk_bf16_f32 %0, %1, %2" : "=v"(r) : "v"(lo), "v"(hi));
    return r;   // low 16 bits = bf16(lo), high = bf16(hi)
}

// ---------------------------------------------------------------------------
// conv_pad: f32 [M_valid x K_valid] (row stride s_row) -> bf16 [Mpad][Kpad],
// zero-padded. Kpad = 1<<kshift.
// ---------------------------------------------------------------------------
__global__ __launch_bounds__(256) void conv_pad(
    const float* __restrict__ src, u16* __restrict__ dst,
    int M_valid, int K_valid, int kshift, int s_row)
{
    i64 i = (i64)blockIdx.x * 256 + threadIdx.x;   // over Mpad*Kpad/4
    int m = (int)(i >> (kshift - 2));
    int k = ((int)(i & ((1 << (kshift - 2)) - 1))) << 2;
    u16x4 hv;
    #pragma unroll
    for (int j = 0; j < 4; ++j) {
        int kk = k + j;
        float x = (m < M_valid && kk < K_valid) ? src[(i64)m * s_row + kk] : 0.f;
        hv[j] = f2b(x);
    }
    *(u16x4*)(dst + ((i64)m << kshift) + k) = hv;
}

// ---------------------------------------------------------------------------
// conv_wout_perm: dst[n][kp] = bf16(w_out[n][(kp&63)*16 + (kp>>6)])
// ---------------------------------------------------------------------------
__global__ __launch_bounds__(256) void conv_wout_perm(
    const float* __restrict__ w, u16* __restrict__ dst)
{
    int i = blockIdx.x * 256 + threadIdx.x;        // over 1024*1024/4
    int n = i >> 8, kp4 = (i & 255) << 2;
    u16x4 hv;
    #pragma unroll
    for (int j = 0; j < 4; ++j) {
        int kp = kp4 + j;
        hv[j] = f2b(w[((i64)n << 10) + ((kp & 63) << 4) + (kp >> 6)]);
    }
    *(u16x4*)(dst + ((i64)n << 10) + kp4) = hv;
}

// ---------------------------------------------------------------------------
// build_kvA: A-panel for the kv-GEMM, transposed to l-contiguous bf16.
// rows 0..1023: A[d][l] = Xb[(l4+b)][d]; rows 1024..1535: A[1024+c][l]=qu[(l4+b)][c]
// ---------------------------------------------------------------------------
__global__ __launch_bounds__(256) void build_kvA(
    const u16* __restrict__ Xb, const u16* __restrict__ qu,
    u16* __restrict__ dst)
{
    const int b = blockIdx.z, r0 = blockIdx.y * 64, l0 = blockIdx.x * 64;
    const int tid = threadIdx.x;
    __shared__ float ts[64][65];
    #pragma unroll
    for (int t = 0; t < 16; ++t) {
        int idx = t * 256 + tid;
        int ch = idx & 63, lr = idx >> 6;
        int lg = l0 + lr;
        float v = 0.f;
        if (lg < 2046) {
            if (r0 < 1024) v = b2f(Xb[((i64)lg * 4 + b) * 1024 + (r0 + ch)]);
            else           v = b2f(qu[((i64)lg * 4 + b) * 512 + (r0 - 1024 + ch)]);
        }
        ts[lr][ch] = v;
    }
    __syncthreads();
    #pragma unroll
    for (int t = 0; t < 16; ++t) {
        int idx = t * 256 + tid;
        int ll = idx & 63, rl = idx >> 6;
        dst[((i64)b * 1536 + r0 + rl) * 2048 + l0 + ll] = f2b(ts[ll][rl]);
    }
}

// ---------------------------------------------------------------------------
// LDS-FREE direct MFMA GEMM: C[m][n] = sum_k A[m][k]*B[n][k].
// 64x256 block tile, 4 waves each owning 64 rows x 64 cols (wc = w*64).
// All fragments loaded DIRECTLY from global (both operands k-contiguous,
// 16B-aligned): A rows read by all 4 waves (L1/L2-temporal reuse), B rows
// once per block. ZERO LDS, ZERO barriers; register-pipelined prefetch
// (distance 1, named even/odd sets). BK=32 per step, 16 MFMA / 8 loads.
// XCD-affine decode keeps each XCD's B slice L2-resident:
//  MODE 0 (q-proj, grid 256): nb=s&1 (B 1MB/XCD);  x0 = qu bf16 (+bias)
//  MODE 1 (kv,    grid 384): nb 2/XCD (B 2MB/XCD); x0 = kT; x1 = vT sigma2
//  MODE 2 (out,   grid 512): nb=s&3 (B 2MB/XCD);   C = out f32 (+bias)
// ---------------------------------------------------------------------------
template<int MODE>
__global__ __launch_bounds__(256) void gemm_bf16(
    const u16* __restrict__ A, i64 a_bs,
    const u16* __restrict__ Bm,
    float* __restrict__ C, const float* __restrict__ bias,
    u16* __restrict__ x0, u16* __restrict__ x1,
    int Krow, int KT, int M_valid)
{
    const int tid = threadIdx.x, lane = tid & 63, w = tid >> 6;
    const int fr = lane & 15, g = lane >> 4;

    const int fid = blockIdx.x;
    const int xcd = fid & 7, s = fid >> 3;
    int nb, mb, bz;
    if (MODE == 0)      { nb = s & 1; mb = xcd * 16 + (s >> 1); bz = 0; }
    else if (MODE == 1) { nb = (xcd & 1) * 2 + (s & 1);
                          int pr = (xcd >> 1) * 24 + (s >> 1); bz = pr / 24; mb = pr % 24; }
    else                { nb = s & 3; int pr = xcd * 16 + (s >> 2); bz = pr >> 5; mb = pr & 31; }

    // per-lane fragment bases (row = fr within 16-row group, k-slot = g*8)
    const u16* Ab = A + (i64)bz * a_bs + ((i64)(mb * 64) + fr) * Krow + g * 8;
    const u16* Bb = Bm + ((i64)(nb * 256 + w * 64) + fr) * Krow + g * 8;

#define LOADF(d, t) do { \
        _Pragma("unroll") \
        for (int mi = 0; mi < 4; ++mi) \
            d[mi] = *(const bf16x8*)(Ab + (i64)(mi * 16) * Krow + (t) * 32); \
        _Pragma("unroll") \
        for (int ni = 0; ni < 4; ++ni) \
            d[4 + ni] = *(const bf16x8*)(Bb + (i64)(ni * 16) * Krow + (t) * 32); \
    } while (0)
#define MF(f) do { \
        _Pragma("unroll") \
        for (int mi = 0; mi < 4; ++mi) \
            _Pragma("unroll") \
            for (int ni = 0; ni < 4; ++ni) \
                acc[mi][ni] = __builtin_amdgcn_mfma_f32_16x16x32_bf16( \
                    f[mi], f[4 + ni], acc[mi][ni], 0, 0, 0); \
    } while (0)

    f32x4 acc[4][4];
    #pragma unroll
    for (int i = 0; i < 4; ++i)
        #pragma unroll
        for (int j = 0; j < 4; ++j)
            acc[i][j] = (f32x4){0.f, 0.f, 0.f, 0.f};

    bf16x8 fe[8], fo[8];
    LOADF(fe, 0);
    for (int kt = 0; kt < KT; kt += 2) {   // KT always even
        LOADF(fo, kt + 1);
        MF(fe);
        if (kt + 2 < KT) LOADF(fe, kt + 2);
        MF(fo);
    }
#undef LOADF
#undef MF

    #pragma unroll
    for (int mi = 0; mi < 4; ++mi)
        #pragma unroll
        for (int ni = 0; ni < 4; ++ni) {
            int gm0 = mb * 64 + mi * 16 + g * 4;
            int gn  = nb * 256 + w * 64 + ni * 16 + fr;
            #pragma unroll
            for (int r = 0; r < 4; ++r) {
                int gm = gm0 + r;
                float val = acc[mi][ni][r];
                if (MODE == 0) {
                    x0[(i64)gm * 512 + gn] = f2b(val + bias[gn]);
                } else if (MODE == 1) {
                    if (gm < 1024) {   // v: channel = e*16+h, sigma2 p-slot
                        int e = gm >> 4, hh = gm & 15;
                        i64 so = ((i64)(bz * 16 + hh) * 64 + e) * 1024
                               + (gn & ~31) + (((gn >> 2) & 3) << 3)
                               + (gn & 3) + (((gn >> 4) & 1) << 2);
                        x1[so] = f2b(val);
                    } else {           // k: channel-1024 = d*16+h
                        int c2 = gm - 1024, d = c2 >> 4, hh = c2 & 15;
                        x0[((i64)(bz * 16 + hh) * 1024 + gn) * 32 + d] = f2b(val);
                    }
                } else {
                    if (gm < M_valid)
                        C[(i64)bz * 1024 + (i64)gm * 4096 + gn] = val + bias[gn];
                }
            }
        }
}

// ---------------------------------------------------------------------------
// MFMA attention (r14 structure): swapped-QK, P-in-register, staged K+V,
// XCD-affine, one barrier/iter. QSCALE applied as f32 mul before exp2.
// ---------------------------------------------------------------------------
__global__ __launch_bounds__(256) void attn_mfma(
    const u16* __restrict__ qu, const u16* __restrict__ kT,
    const u16* __restrict__ vT, u16* __restrict__ attA)
{
    const int g0 = blockIdx.x;
    const int xcd = g0 & 7, sub = g0 >> 3;
    const int lblk = sub & 15;                  // same bh for 16 consecutive
    const int bh = xcd + ((sub >> 4) << 3);     // 8 bh per XCD
    const int b = bh >> 4, h = bh & 15;
    const int tid = threadIdx.x, lane = tid & 63, w = tid >> 6;   // 0..3
    const int fr = lane & 15, g = lane >> 4;
    const int l0 = lblk * 128 + w * 32;

    __shared__ __align__(16) u16 kbuf[2][2560];    // 64 rows x 40 u16 (80B pitch)
    __shared__ __align__(16) u16 vbuf[2][4608];    // 64 rows x 72 u16 (144B pitch)

    // Q fragments (B operand): n = l = fr within tile mf, d-slots g*8..
    bf16x8 aq[2];
    #pragma unroll
    for (int mf = 0; mf < 2; ++mf)
        aq[mf] = *(const bf16x8*)(qu + ((i64)((l0 + mf * 16 + fr) * 4 + b) * 512
                                        + h * 32 + g * 8));   // row = l*4+b

    const f32x4 zf = {0.f, 0.f, 0.f, 0.f};

    // staging constants: row sr = tid>>2 (0..63), chunk sc = tid&3
    const int sr = tid >> 2, sc = tid & 3;
    const u16* ksrc = kT + (i64)bh * 32768 + sr * 32 + sc * 8;     // + t*2048
    char* kdst = (char*)&kbuf[0][0] + sr * 80 + sc * 16;           // + buf*5120
    const u16* vsrc = vT + (i64)bh * 65536 + (i64)sr * 1024 + sc * 8;  // + t*64
    char* vdst = (char*)&vbuf[0][0] + sr * 144 + sc * 16;          // + buf*9216

    // prologue: stage tile 0 into buffer 0
    *(u32x4*)kdst = *(const u32x4*)ksrc;
    *(u32x4*)vdst = *(const u32x4*)vsrc;
    *(u32x4*)(vdst + 64) = *(const u32x4*)(vsrc + 32);
    __syncthreads();

    float l_part[2] = {0.f, 0.f};
    f32x4 o[2][4];
    #pragma unroll
    for (int mf = 0; mf < 2; ++mf)
        #pragma unroll
        for (int nf = 0; nf < 4; ++nf)
            o[mf][nf] = zf;

    for (int t = 0; t < 16; ++t) {
        const int cur = t & 1;
        const int tn = (t < 15) ? t + 1 : 15;

        // 1. issue next-tile global loads (consumed by ds_write below)
        u32x4 knx  = *(const u32x4*)(ksrc + tn * 2048);
        u32x4 vnx0 = *(const u32x4*)(vsrc + tn * 64);
        u32x4 vnx1 = *(const u32x4*)(vsrc + tn * 64 + 32);

        // 2. QK(t) from LDS K, swapped operands: T[mf][nf] rows=p, cols=l
        const char* kc_ = (const char*)&kbuf[cur][0];
        f32x4 s[2][4];
        __builtin_amdgcn_s_setprio(1);
        #pragma unroll
        for (int nf = 0; nf < 4; ++nf) {
            bf16x8 ak = *(const bf16x8*)(kc_ + (nf * 16 + fr) * 80 + g * 16);
            s[0][nf] = __builtin_amdgcn_mfma_f32_16x16x32_bf16(ak, aq[0], zf, 0, 0, 0);
            s[1][nf] = __builtin_amdgcn_mfma_f32_16x16x32_bf16(ak, aq[1], zf, 0, 0, 0);
        }
        __builtin_amdgcn_s_setprio(0);

        // 3. scale + exp2 + pack straight into PV A-fragment words
        u32x4 ppk[2][2];
        #pragma unroll
        for (int mf = 0; mf < 2; ++mf)
            #pragma unroll
            for (int nf = 0; nf < 4; ++nf) {
                float p_[4];
                #pragma unroll
                for (int r = 0; r < 4; ++r) p_[r] = EXP2(QSCALE * s[mf][nf][r]);
                l_part[mf] += (p_[0] + p_[1]) + (p_[2] + p_[3]);
                ppk[mf][nf >> 1][(nf & 1) * 2 + 0] = cvt_pk_bf16(p_[0], p_[1]);
                ppk[mf][nf >> 1][(nf & 1) * 2 + 1] = cvt_pk_bf16(p_[2], p_[3]);
            }

        // 4. write staged tile t+1 into the other buffers
        {
            const int nb_ = cur ^ 1;
            *(u32x4*)(kdst + nb_ * 5120) = knx;
            *(u32x4*)(vdst + nb_ * 9216) = vnx0;
            *(u32x4*)(vdst + nb_ * 9216 + 64) = vnx1;
        }

        // 5. PV(t): A = packed P (m = l = fr), B = V fragment from LDS (n = e)
        const char* vc_ = (const char*)&vbuf[cur][0];
        __builtin_amdgcn_s_setprio(1);
        #pragma unroll
        for (int ks = 0; ks < 2; ++ks) {
            bf16x8 ap0 = __builtin_bit_cast(bf16x8, ppk[0][ks]);
            bf16x8 ap1 = __builtin_bit_cast(bf16x8, ppk[1][ks]);
            #pragma unroll
            for (int nf = 0; nf < 4; ++nf) {
                bf16x8 bv = *(const bf16x8*)(vc_ + (nf * 16 + fr) * 144
                                                 + ks * 64 + g * 16);
                o[0][nf] = __builtin_amdgcn_mfma_f32_16x16x32_bf16(ap0, bv, o[0][nf], 0, 0, 0);
                o[1][nf] = __builtin_amdgcn_mfma_f32_16x16x32_bf16(ap1, bv, o[1][nf], 0, 0, 0);
            }
        }
        __builtin_amdgcn_s_setprio(0);

        __syncthreads();   // buf[cur] reads done; buf[cur^1] writes visible
    }

    // row-sum totals: lane holds l_part for l = mf*16 + fr; reduce over g
    #pragma unroll
    for (int mf = 0; mf < 2; ++mf) {
        l_part[mf] += __shfl_xor(l_part[mf], 16);
        l_part[mf] += __shfl_xor(l_part[mf], 32);
    }
    // output: o rows l = mf*16 + 4g + r, cols e = nf*16 + fr
    #pragma unroll
    for (int mf = 0; mf < 2; ++mf)
        #pragma unroll
        for (int r = 0; r < 4; ++r) {
            int l = l0 + mf * 16 + g * 4 + r;
            float tot = __shfl(l_part[mf], g * 4 + r);   // lane fr = 4g+r has it
            if (l < 2046) {
                float inv = 1.f / tot;
                #pragma unroll
                for (int nf = 0; nf < 4; ++nf)
                    attA[((i64)b * 2048 + l) * 1024 + h * 64 + nf * 16 + fr]
                        = f2b(o[mf][nf][r] * inv);
            }
        }
}

// ---------------------------------------------------------------------------
// launch
// ---------------------------------------------------------------------------
extern "C" void kernel_launch(void* const* d_in, const int* in_sizes, int n_in,
                              void* d_out, int out_size, void* d_ws, size_t ws_size,
                              hipStream_t stream) {
    const float* input = (const float*)d_in[0];  // [2046][4][1024]
    const float* w_kv  = (const float*)d_in[1];  // [1024][2048]
    const float* w_q   = (const float*)d_in[2];  // [512][1024]
    const float* b_q   = (const float*)d_in[3];  // [512]
    const float* w_out = (const float*)d_in[4];  // [1024][1024]
    const float* b_out = (const float*)d_in[5];  // [1024]
    float* out = (float*)d_out;                  // [2046][4][1024]

    char* W = (char*)d_ws;
    u16* Xb      = (u16*)(W + 16777216);     // 8192x1024      (16 MB)
    u16* qu      = (u16*)(W + 33554432);     // 8192x512       (8 MB) unscaled
    u16* wq_b    = (u16*)(W + 41943040);     // 512x1024       (1 MB)
    u16* wkv_b   = (u16*)(W + 42991616);     // 1024x2048      (4 MB)
    u16* wout_b  = (u16*)(W + 47185920);     // 1024x1024      (2 MB)
    u16* kvA     = (u16*)(W + 49283072);     // 4x1536x2048    (24 MB)
    u16* kT      = (u16*)(W + 74448896);     // 4x16x1024x32   (4 MB)
    u16* vT      = (u16*)(W + 78643200);     // 4x16x64x1024   (8 MB)
    u16* attA    = (u16*)(W + 87031808);     // 4x2048x1024    (16 MB)

    dim3 blk(256);

    // bf16 conversions (independent)
    conv_pad<<<8192, blk, 0, stream>>>(input, Xb, 8184, 1024, 10, 1024);
    conv_pad<<<512,  blk, 0, stream>>>(w_q, wq_b, 512, 1024, 10, 1024);
    conv_pad<<<2048, blk, 0, stream>>>(w_kv, wkv_b, 1024, 2046, 11, 2048);
    conv_wout_perm<<<1024, blk, 0, stream>>>(w_out, wout_b);

    // q' = X @ w_q^T + b_q -> qu bf16 (unscaled)
    gemm_bf16<0><<<dim3(256), blk, 0, stream>>>(
        Xb, 0, wq_b, nullptr, b_q, qu, nullptr, 1024, 32, 8192);

    // combined kv A-panel (Xb + qu, transposed bf16)
    build_kvA<<<dim3(32, 24, 4), blk, 0, stream>>>(Xb, qu, kvA);

    // [v;k] = kvA @ wkv_b^T -> kT/vT bf16 (per b; vT in sigma2 layout)
    gemm_bf16<1><<<dim3(384), blk, 0, stream>>>(
        kvA, (i64)1536 * 2048, wkv_b, nullptr, nullptr, kT, vT, 2048, 64, 1536);

    // attention -> attA bf16 (swapped-QK, P-in-register, staged K+V)
    attn_mfma<<<dim3(1024), blk, 0, stream>>>(qu, kT, vT, attA);

    // out = attA @ wout_b^T + b_out (per b)
    gemm_bf16<2><<<dim3(512), blk, 0, stream>>>(
        attA, (i64)2048 * 1024, wout_b, out, b_out, nullptr, nullptr, 1024, 32, 2046);
}

// Round 19
// 169.171 us; speedup vs baseline: 1.8753x; 1.8753x over previous
//
#include <hip/hip_runtime.h>
#include <hip/hip_bf16.h>

typedef long long i64;
typedef unsigned int uint;
using u16 = unsigned short;
using f32x4  = __attribute__((ext_vector_type(4))) float;
using bf16x8 = __attribute__((ext_vector_type(8))) short;
using u32x4  = __attribute__((ext_vector_type(4))) uint;
using u16x4  = __attribute__((ext_vector_type(4))) u16;

// 0.125 (attention scaling) * log2(e): applied as an f32 mul on scores so
// softmax uses exp2 directly. Softmax is invariant to the base change.
#define QSCALE 0.18033688011112042f

#if __has_builtin(__builtin_amdgcn_exp2f)
#define EXP2(x) __builtin_amdgcn_exp2f(x)   // raw v_exp_f32 (scores are O(20))
#else
#define EXP2(x) __builtin_exp2f(x)
#endif

__device__ __forceinline__ u16 f2b(float x) {   // f32 -> bf16 RNE
    uint u = __float_as_uint(x);
    return (u16)((u + 0x7FFFu + ((u >> 16) & 1u)) >> 16);
}
__device__ __forceinline__ float b2f(u16 h) {
    return __uint_as_float((uint)h << 16);
}
__device__ __forceinline__ uint cvt_pk_bf16(float lo, float hi) {
    uint r;
    asm("v_cvt_pk_bf16_f32 %0, %1, %2" : "=v"(r) : "v"(lo), "v"(hi));
    return r;   // low 16 bits = bf16(lo), high = bf16(hi)
}

// ---------------------------------------------------------------------------
// fused conversions: one dispatch covering all four weight/input conversions.
// ---------------------------------------------------------------------------
__device__ __forceinline__ void conv_pad_dev(
    int bid, const float* __restrict__ src, u16* __restrict__ dst,
    int M_valid, int K_valid, int kshift, int s_row)
{
    i64 i = (i64)bid * 256 + threadIdx.x;          // over Mpad*Kpad/4
    int m = (int)(i >> (kshift - 2));
    int k = ((int)(i & ((1 << (kshift - 2)) - 1))) << 2;
    u16x4 hv;
    #pragma unroll
    for (int j = 0; j < 4; ++j) {
        int kk = k + j;
        float x = (m < M_valid && kk < K_valid) ? src[(i64)m * s_row + kk] : 0.f;
        hv[j] = f2b(x);
    }
    *(u16x4*)(dst + ((i64)m << kshift) + k) = hv;
}
__device__ __forceinline__ void conv_wout_dev(
    int bid, const float* __restrict__ w, u16* __restrict__ dst)
{
    int i = bid * 256 + threadIdx.x;               // over 1024*1024/4
    int n = i >> 8, kp4 = (i & 255) << 2;
    u16x4 hv;
    #pragma unroll
    for (int j = 0; j < 4; ++j) {
        int kp = kp4 + j;
        hv[j] = f2b(w[((i64)n << 10) + ((kp & 63) << 4) + (kp >> 6)]);
    }
    *(u16x4*)(dst + ((i64)n << 10) + kp4) = hv;
}
__global__ __launch_bounds__(256) void conv_all(
    const float* __restrict__ X, const float* __restrict__ wq,
    const float* __restrict__ wkv, const float* __restrict__ wout,
    u16* __restrict__ Xb, u16* __restrict__ wq_b,
    u16* __restrict__ wkv_b, u16* __restrict__ wout_b)
{
    const int bid = blockIdx.x;
    if (bid < 8192)       conv_pad_dev(bid, X, Xb, 8184, 1024, 10, 1024);
    else if (bid < 8704)  conv_pad_dev(bid - 8192, wq, wq_b, 512, 1024, 10, 1024);
    else if (bid < 10752) conv_pad_dev(bid - 8704, wkv, wkv_b, 1024, 2046, 11, 2048);
    else                  conv_wout_dev(bid - 10752, wout, wout_b);
}

// ---------------------------------------------------------------------------
// build_kvA: A-panel for the kv-GEMM, transposed to l-contiguous bf16.
// rows 0..1023: A[d][l] = Xb[(l4+b)][d]; rows 1024..1535: A[1024+c][l]=qu[(l4+b)][c]
// ---------------------------------------------------------------------------
__global__ __launch_bounds__(256) void build_kvA(
    const u16* __restrict__ Xb, const u16* __restrict__ qu,
    u16* __restrict__ dst)
{
    const int b = blockIdx.z, r0 = blockIdx.y * 64, l0 = blockIdx.x * 64;
    const int tid = threadIdx.x;
    __shared__ float ts[64][65];
    #pragma unroll
    for (int t = 0; t < 16; ++t) {
        int idx = t * 256 + tid;
        int ch = idx & 63, lr = idx >> 6;
        int lg = l0 + lr;
        float v = 0.f;
        if (lg < 2046) {
            if (r0 < 1024) v = b2f(Xb[((i64)lg * 4 + b) * 1024 + (r0 + ch)]);
            else           v = b2f(qu[((i64)lg * 4 + b) * 512 + (r0 - 1024 + ch)]);
        }
        ts[lr][ch] = v;
    }
    __syncthreads();
    #pragma unroll
    for (int t = 0; t < 16; ++t) {
        int idx = t * 256 + tid;
        int ll = idx & 63, rl = idx >> 6;
        dst[((i64)b * 1536 + r0 + rl) * 2048 + l0 + ll] = f2b(ts[ll][rl]);
    }
}

// ---------------------------------------------------------------------------
// Plain-bf16 MFMA GEMM, 64x128 tile, BK=64 (r16 structure): C = A*B^T.
// 4 waves: wave covers A-rows (w&1)*32..+32, B-cols (w>>1)*64..+64.
// LDS rows 128B pitch, chunk swizzle c^(row&7) applied on the GLOBAL source;
// 2 barriers per 32 MFMAs/wave, reg-prefetch distance 1.
// FIXED XCD decode: each XCD owns ONE B-panel (nb = xcd) so the 512KB/1MB
// B-panel stays L2-resident while A streams through (r15/r16's decode leaked
// all 8 B-panels into every XCD's L2).
//  MODE 0 (q-proj, grid 512):  nb = xcd>>1 (4 panels / 8 XCDs)
//  MODE 1 (kv,     grid 768):  nb = xcd (8 panels)
//  MODE 2 (out,    grid 1024): nb = xcd (8 panels)
// ---------------------------------------------------------------------------
template<int MODE>
__global__ __launch_bounds__(256) void gemm_bf16(
    const u16* __restrict__ A, i64 a_bs,
    const u16* __restrict__ Bm,
    float* __restrict__ C, const float* __restrict__ bias,
    u16* __restrict__ x0, u16* __restrict__ x1,
    int Krow, int KT, int M_valid)
{
    __shared__ __align__(16) u16 As[4096], Bs[8192];   // 64 / 128 rows x 64 k
    const int tid = threadIdx.x, lane = tid & 63, w = tid >> 6;
    const int fr = lane & 15, g = lane >> 4;

    // grid decode: ONE B-panel per XCD; mb/bz walk within the XCD
    const int fid = blockIdx.x;
    const int xcd = fid & 7, s = fid >> 3;
    int nb, mb, bz;
    if (MODE == 0)      { nb = xcd >> 1; mb = (xcd & 1) * 64 + s; bz = 0; }   // s 0..63
    else if (MODE == 1) { nb = xcd; mb = s % 24; bz = s / 24; }               // s 0..95
    else                { nb = xcd; mb = s & 31; bz = s >> 5; }               // s 0..127

    // flat staging: per thread 2 A chunks + 4 B chunks (16B each)
    const int srow = tid >> 3, sch = tid & 7;          // 32 rows/round, chunk 0..7
    const int scol = (sch ^ (srow & 7)) << 3;          // pre-swizzled src chunk
    const u16* Asrc = A + (i64)bz * a_bs + ((i64)mb * 64 + srow) * Krow + scol;
    const u16* Bsrc = Bm + ((i64)nb * 128 + srow) * Krow + scol;
    char* Adst = (char*)As + srow * 128 + sch * 16;
    char* Bdst = (char*)Bs + srow * 128 + sch * 16;

    f32x4 acc[2][4];
    #pragma unroll
    for (int i = 0; i < 2; ++i)
        #pragma unroll
        for (int j = 0; j < 4; ++j)
            acc[i][j] = (f32x4){0.f, 0.f, 0.f, 0.f};

    u32x4 st[6];
    st[0] = *(const u32x4*)(Asrc);
    st[1] = *(const u32x4*)(Asrc + (i64)32 * Krow);
    #pragma unroll
    for (int it = 0; it < 4; ++it)
        st[2 + it] = *(const u32x4*)(Bsrc + (i64)(it * 32) * Krow);

    const int wr = (w & 1) * 32, wc = (w >> 1) * 64;   // compute role

    for (int kt = 0; kt < KT; ++kt) {
        __syncthreads();
        *(u32x4*)(Adst) = st[0];
        *(u32x4*)(Adst + 32 * 128) = st[1];
        #pragma unroll
        for (int it = 0; it < 4; ++it)
            *(u32x4*)(Bdst + it * 32 * 128) = st[2 + it];
        __syncthreads();
        if (kt + 1 < KT) {
            st[0] = *(const u32x4*)(Asrc + (kt + 1) * 64);
            st[1] = *(const u32x4*)(Asrc + (i64)32 * Krow + (kt + 1) * 64);
            #pragma unroll
            for (int it = 0; it < 4; ++it)
                st[2 + it] = *(const u32x4*)(Bsrc + (i64)(it * 32) * Krow
                                                  + (kt + 1) * 64);
        }
        #pragma unroll
        for (int half = 0; half < 2; ++half) {
            bf16x8 ah[2], bh[4];
            #pragma unroll
            for (int mi = 0; mi < 2; ++mi) {
                int rr = wr + mi * 16 + fr;
                ah[mi] = *(const bf16x8*)((const char*)As + rr * 128
                                          + (((half * 4 + g) ^ (rr & 7)) << 4));
            }
            #pragma unroll
            for (int ni = 0; ni < 4; ++ni) {
                int rr = wc + ni * 16 + fr;
                bh[ni] = *(const bf16x8*)((const char*)Bs + rr * 128
                                          + (((half * 4 + g) ^ (rr & 7)) << 4));
            }
            #pragma unroll
            for (int mi = 0; mi < 2; ++mi)
                #pragma unroll
                for (int ni = 0; ni < 4; ++ni)
                    acc[mi][ni] = __builtin_amdgcn_mfma_f32_16x16x32_bf16(
                        ah[mi], bh[ni], acc[mi][ni], 0, 0, 0);
        }
    }

    #pragma unroll
    for (int mi = 0; mi < 2; ++mi)
        #pragma unroll
        for (int ni = 0; ni < 4; ++ni) {
            int gm0 = mb * 64 + wr + mi * 16 + g * 4;
            int gn  = nb * 128 + wc + ni * 16 + fr;
            #pragma unroll
            for (int r = 0; r < 4; ++r) {
                int gm = gm0 + r;
                float val = acc[mi][ni][r];
                if (MODE == 0) {
                    x0[(i64)gm * 512 + gn] = f2b(val + bias[gn]);
                } else if (MODE == 1) {
                    if (gm < 1024) {   // v: channel = e*16+h, sigma2 p-slot
                        int e = gm >> 4, hh = gm & 15;
                        i64 so = ((i64)(bz * 16 + hh) * 64 + e) * 1024
                               + (gn & ~31) + (((gn >> 2) & 3) << 3)
                               + (gn & 3) + (((gn >> 4) & 1) << 2);
                        x1[so] = f2b(val);
                    } else {           // k: channel-1024 = d*16+h
                        int c2 = gm - 1024, d = c2 >> 4, hh = c2 & 15;
                        x0[((i64)(bz * 16 + hh) * 1024 + gn) * 32 + d] = f2b(val);
                    }
                } else {
                    if (gm < M_valid)
                        C[(i64)bz * 1024 + (i64)gm * 4096 + gn] = val + bias[gn];
                }
            }
        }
}

// ---------------------------------------------------------------------------
// MFMA attention (r14 structure): swapped-QK, P-in-register, staged K+V,
// XCD-affine, one barrier/iter. QSCALE applied as f32 mul before exp2.
// ---------------------------------------------------------------------------
__global__ __launch_bounds__(256) void attn_mfma(
    const u16* __restrict__ qu, const u16* __restrict__ kT,
    const u16* __restrict__ vT, u16* __restrict__ attA)
{
    const int g0 = blockIdx.x;
    const int xcd = g0 & 7, sub = g0 >> 3;
    const int lblk = sub & 15;                  // same bh for 16 consecutive
    const int bh = xcd + ((sub >> 4) << 3);     // 8 bh per XCD
    const int b = bh >> 4, h = bh & 15;
    const int tid = threadIdx.x, lane = tid & 63, w = tid >> 6;   // 0..3
    const int fr = lane & 15, g = lane >> 4;
    const int l0 = lblk * 128 + w * 32;

    __shared__ __align__(16) u16 kbuf[2][2560];    // 64 rows x 40 u16 (80B pitch)
    __shared__ __align__(16) u16 vbuf[2][4608];    // 64 rows x 72 u16 (144B pitch)

    // Q fragments (B operand): n = l = fr within tile mf, d-slots g*8..
    bf16x8 aq[2];
    #pragma unroll
    for (int mf = 0; mf < 2; ++mf)
        aq[mf] = *(const bf16x8*)(qu + ((i64)((l0 + mf * 16 + fr) * 4 + b) * 512
                                        + h * 32 + g * 8));   // row = l*4+b

    const f32x4 zf = {0.f, 0.f, 0.f, 0.f};

    // staging constants: row sr = tid>>2 (0..63), chunk sc = tid&3
    const int sr = tid >> 2, sc = tid & 3;
    const u16* ksrc = kT + (i64)bh * 32768 + sr * 32 + sc * 8;     // + t*2048
    char* kdst = (char*)&kbuf[0][0] + sr * 80 + sc * 16;           // + buf*5120
    const u16* vsrc = vT + (i64)bh * 65536 + (i64)sr * 1024 + sc * 8;  // + t*64
    char* vdst = (char*)&vbuf[0][0] + sr * 144 + sc * 16;          // + buf*9216

    // prologue: stage tile 0 into buffer 0
    *(u32x4*)kdst = *(const u32x4*)ksrc;
    *(u32x4*)vdst = *(const u32x4*)vsrc;
    *(u32x4*)(vdst + 64) = *(const u32x4*)(vsrc + 32);
    __syncthreads();

    float l_part[2] = {0.f, 0.f};
    f32x4 o[2][4];
    #pragma unroll
    for (int mf = 0; mf < 2; ++mf)
        #pragma unroll
        for (int nf = 0; nf < 4; ++nf)
            o[mf][nf] = zf;

    for (int t = 0; t < 16; ++t) {
        const int cur = t & 1;
        const int tn = (t < 15) ? t + 1 : 15;

        // 1. issue next-tile global loads (consumed by ds_write below)
        u32x4 knx  = *(const u32x4*)(ksrc + tn * 2048);
        u32x4 vnx0 = *(const u32x4*)(vsrc + tn * 64);
        u32x4 vnx1 = *(const u32x4*)(vsrc + tn * 64 + 32);

        // 2. QK(t) from LDS K, swapped operands: T[mf][nf] rows=p, cols=l
        const char* kc_ = (const char*)&kbuf[cur][0];
        f32x4 s[2][4];
        __builtin_amdgcn_s_setprio(1);
        #pragma unroll
        for (int nf = 0; nf < 4; ++nf) {
            bf16x8 ak = *(const bf16x8*)(kc_ + (nf * 16 + fr) * 80 + g * 16);
            s[0][nf] = __builtin_amdgcn_mfma_f32_16x16x32_bf16(ak, aq[0], zf, 0, 0, 0);
            s[1][nf] = __builtin_amdgcn_mfma_f32_16x16x32_bf16(ak, aq[1], zf, 0, 0, 0);
        }
        __builtin_amdgcn_s_setprio(0);

        // 3. scale + exp2 + pack straight into PV A-fragment words
        u32x4 ppk[2][2];
        #pragma unroll
        for (int mf = 0; mf < 2; ++mf)
            #pragma unroll
            for (int nf = 0; nf < 4; ++nf) {
                float p_[4];
                #pragma unroll
                for (int r = 0; r < 4; ++r) p_[r] = EXP2(QSCALE * s[mf][nf][r]);
                l_part[mf] += (p_[0] + p_[1]) + (p_[2] + p_[3]);
                ppk[mf][nf >> 1][(nf & 1) * 2 + 0] = cvt_pk_bf16(p_[0], p_[1]);
                ppk[mf][nf >> 1][(nf & 1) * 2 + 1] = cvt_pk_bf16(p_[2], p_[3]);
            }

        // 4. write staged tile t+1 into the other buffers
        {
            const int nb_ = cur ^ 1;
            *(u32x4*)(kdst + nb_ * 5120) = knx;
            *(u32x4*)(vdst + nb_ * 9216) = vnx0;
            *(u32x4*)(vdst + nb_ * 9216 + 64) = vnx1;
        }

        // 5. PV(t): A = packed P (m = l = fr), B = V fragment from LDS (n = e)
        const char* vc_ = (const char*)&vbuf[cur][0];
        __builtin_amdgcn_s_setprio(1);
        #pragma unroll
        for (int ks = 0; ks < 2; ++ks) {
            bf16x8 ap0 = __builtin_bit_cast(bf16x8, ppk[0][ks]);
            bf16x8 ap1 = __builtin_bit_cast(bf16x8, ppk[1][ks]);
            #pragma unroll
            for (int nf = 0; nf < 4; ++nf) {
                bf16x8 bv = *(const bf16x8*)(vc_ + (nf * 16 + fr) * 144
                                                 + ks * 64 + g * 16);
                o[0][nf] = __builtin_amdgcn_mfma_f32_16x16x32_bf16(ap0, bv, o[0][nf], 0, 0, 0);
                o[1][nf] = __builtin_amdgcn_mfma_f32_16x16x32_bf16(ap1, bv, o[1][nf], 0, 0, 0);
            }
        }
        __builtin_amdgcn_s_setprio(0);

        __syncthreads();   // buf[cur] reads done; buf[cur^1] writes visible
    }

    // row-sum totals: lane holds l_part for l = mf*16 + fr; reduce over g
    #pragma unroll
    for (int mf = 0; mf < 2; ++mf) {
        l_part[mf] += __shfl_xor(l_part[mf], 16);
        l_part[mf] += __shfl_xor(l_part[mf], 32);
    }
    // output: o rows l = mf*16 + 4g + r, cols e = nf*16 + fr
    #pragma unroll
    for (int mf = 0; mf < 2; ++mf)
        #pragma unroll
        for (int r = 0; r < 4; ++r) {
            int l = l0 + mf * 16 + g * 4 + r;
            float tot = __shfl(l_part[mf], g * 4 + r);   // lane fr = 4g+r has it
            if (l < 2046) {
                float inv = 1.f / tot;
                #pragma unroll
                for (int nf = 0; nf < 4; ++nf)
                    attA[((i64)b * 2048 + l) * 1024 + h * 64 + nf * 16 + fr]
                        = f2b(o[mf][nf][r] * inv);
            }
        }
}

// ---------------------------------------------------------------------------
// launch
// ---------------------------------------------------------------------------
extern "C" void kernel_launch(void* const* d_in, const int* in_sizes, int n_in,
                              void* d_out, int out_size, void* d_ws, size_t ws_size,
                              hipStream_t stream) {
    const float* input = (const float*)d_in[0];  // [2046][4][1024]
    const float* w_kv  = (const float*)d_in[1];  // [1024][2048]
    const float* w_q   = (const float*)d_in[2];  // [512][1024]
    const float* b_q   = (const float*)d_in[3];  // [512]
    const float* w_out = (const float*)d_in[4];  // [1024][1024]
    const float* b_out = (const float*)d_in[5];  // [1024]
    float* out = (float*)d_out;                  // [2046][4][1024]

    char* W = (char*)d_ws;
    u16* Xb      = (u16*)(W + 16777216);     // 8192x1024      (16 MB)
    u16* qu      = (u16*)(W + 33554432);     // 8192x512       (8 MB) unscaled
    u16* wq_b    = (u16*)(W + 41943040);     // 512x1024       (1 MB)
    u16* wkv_b   = (u16*)(W + 42991616);     // 1024x2048      (4 MB)
    u16* wout_b  = (u16*)(W + 47185920);     // 1024x1024      (2 MB)
    u16* kvA     = (u16*)(W + 49283072);     // 4x1536x2048    (24 MB)
    u16* kT      = (u16*)(W + 74448896);     // 4x16x1024x32   (4 MB)
    u16* vT      = (u16*)(W + 78643200);     // 4x16x64x1024   (8 MB)
    u16* attA    = (u16*)(W + 87031808);     // 4x2048x1024    (16 MB)

    dim3 blk(256);

    // all bf16 conversions in ONE dispatch
    conv_all<<<dim3(11776), blk, 0, stream>>>(
        input, w_q, w_kv, w_out, Xb, wq_b, wkv_b, wout_b);

    // q' = X @ w_q^T + b_q -> qu bf16 (unscaled)
    gemm_bf16<0><<<dim3(512), blk, 0, stream>>>(
        Xb, 0, wq_b, nullptr, b_q, qu, nullptr, 1024, 16, 8192);

    // combined kv A-panel (Xb + qu, transposed bf16)
    build_kvA<<<dim3(32, 24, 4), blk, 0, stream>>>(Xb, qu, kvA);

    // [v;k] = kvA @ wkv_b^T -> kT/vT bf16 (per b; vT in sigma2 layout)
    gemm_bf16<1><<<dim3(768), blk, 0, stream>>>(
        kvA, (i64)1536 * 2048, wkv_b, nullptr, nullptr, kT, vT, 2048, 32, 1536);

    // attention -> attA bf16 (swapped-QK, P-in-register, staged K+V)
    attn_mfma<<<dim3(1024), blk, 0, stream>>>(qu, kT, vT, attA);

    // out = attA @ wout_b^T + b_out (per b)
    gemm_bf16<2><<<dim3(1024), blk, 0, stream>>>(
        attA, (i64)2048 * 1024, wout_b, out, b_out, nullptr, nullptr, 1024, 16, 2046);
}

// Round 20
// 160.885 us; speedup vs baseline: 1.9719x; 1.0515x over previous
//
#include <hip/hip_runtime.h>
#include <hip/hip_bf16.h>

typedef long long i64;
typedef unsigned int uint;
using u16 = unsigned short;
using f32x4  = __attribute__((ext_vector_type(4))) float;
using bf16x8 = __attribute__((ext_vector_type(8))) short;
using u32x4  = __attribute__((ext_vector_type(4))) uint;
using u16x4  = __attribute__((ext_vector_type(4))) u16;

// 0.125 (attention scaling) * log2(e): applied as an f32 mul on scores so
// softmax uses exp2 directly. Softmax is invariant to the base change.
#define QSCALE 0.18033688011112042f

#if __has_builtin(__builtin_amdgcn_exp2f)
#define EXP2(x) __builtin_amdgcn_exp2f(x)   // raw v_exp_f32 (scores are O(20))
#else
#define EXP2(x) __builtin_exp2f(x)
#endif

__device__ __forceinline__ u16 f2b(float x) {   // f32 -> bf16 RNE
    uint u = __float_as_uint(x);
    return (u16)((u + 0x7FFFu + ((u >> 16) & 1u)) >> 16);
}
__device__ __forceinline__ float b2f(u16 h) {
    return __uint_as_float((uint)h << 16);
}
__device__ __forceinline__ uint cvt_pk_bf16(float lo, float hi) {
    uint r;
    asm("v_cvt_pk_bf16_f32 %0, %1, %2" : "=v"(r) : "v"(lo), "v"(hi));
    return r;   // low 16 bits = bf16(lo), high = bf16(hi)
}

// ---------------------------------------------------------------------------
// fused conversions: one dispatch covering all four weight/input conversions.
// ---------------------------------------------------------------------------
__device__ __forceinline__ void conv_pad_dev(
    int bid, const float* __restrict__ src, u16* __restrict__ dst,
    int M_valid, int K_valid, int kshift, int s_row)
{
    i64 i = (i64)bid * 256 + threadIdx.x;          // over Mpad*Kpad/4
    int m = (int)(i >> (kshift - 2));
    int k = ((int)(i & ((1 << (kshift - 2)) - 1))) << 2;
    u16x4 hv;
    #pragma unroll
    for (int j = 0; j < 4; ++j) {
        int kk = k + j;
        float x = (m < M_valid && kk < K_valid) ? src[(i64)m * s_row + kk] : 0.f;
        hv[j] = f2b(x);
    }
    *(u16x4*)(dst + ((i64)m << kshift) + k) = hv;
}
__device__ __forceinline__ void conv_wout_dev(
    int bid, const float* __restrict__ w, u16* __restrict__ dst)
{
    int i = bid * 256 + threadIdx.x;               // over 1024*1024/4
    int n = i >> 8, kp4 = (i & 255) << 2;
    u16x4 hv;
    #pragma unroll
    for (int j = 0; j < 4; ++j) {
        int kp = kp4 + j;
        hv[j] = f2b(w[((i64)n << 10) + ((kp & 63) << 4) + (kp >> 6)]);
    }
    *(u16x4*)(dst + ((i64)n << 10) + kp4) = hv;
}
__global__ __launch_bounds__(256) void conv_all(
    const float* __restrict__ X, const float* __restrict__ wq,
    const float* __restrict__ wkv, const float* __restrict__ wout,
    u16* __restrict__ Xb, u16* __restrict__ wq_b,
    u16* __restrict__ wkv_b, u16* __restrict__ wout_b)
{
    const int bid = blockIdx.x;
    if (bid < 8192)       conv_pad_dev(bid, X, Xb, 8184, 1024, 10, 1024);
    else if (bid < 8704)  conv_pad_dev(bid - 8192, wq, wq_b, 512, 1024, 10, 1024);
    else if (bid < 10752) conv_pad_dev(bid - 8704, wkv, wkv_b, 1024, 2046, 11, 2048);
    else                  conv_wout_dev(bid - 10752, wout, wout_b);
}

// ---------------------------------------------------------------------------
// build_kvA: A-panel for the kv-GEMM, transposed to l-contiguous bf16.
// rows 0..1023: A[d][l] = Xb[(l4+b)][d]; rows 1024..1535: A[1024+c][l]=qu[(l4+b)][c]
// ---------------------------------------------------------------------------
__global__ __launch_bounds__(256) void build_kvA(
    const u16* __restrict__ Xb, const u16* __restrict__ qu,
    u16* __restrict__ dst)
{
    const int b = blockIdx.z, r0 = blockIdx.y * 64, l0 = blockIdx.x * 64;
    const int tid = threadIdx.x;
    __shared__ float ts[64][65];
    #pragma unroll
    for (int t = 0; t < 16; ++t) {
        int idx = t * 256 + tid;
        int ch = idx & 63, lr = idx >> 6;
        int lg = l0 + lr;
        float v = 0.f;
        if (lg < 2046) {
            if (r0 < 1024) v = b2f(Xb[((i64)lg * 4 + b) * 1024 + (r0 + ch)]);
            else           v = b2f(qu[((i64)lg * 4 + b) * 512 + (r0 - 1024 + ch)]);
        }
        ts[lr][ch] = v;
    }
    __syncthreads();
    #pragma unroll
    for (int t = 0; t < 16; ++t) {
        int idx = t * 256 + tid;
        int ll = idx & 63, rl = idx >> 6;
        dst[((i64)b * 1536 + r0 + rl) * 2048 + l0 + ll] = f2b(ts[ll][rl]);
    }
}

// ---------------------------------------------------------------------------
// Plain-bf16 MFMA GEMM, 64x128 tile, BK=64 (r16 structure): C = A*B^T.
// 4 waves: wave covers A-rows (w&1)*32..+32, B-cols (w>>1)*64..+64.
// LDS rows 128B pitch, chunk swizzle c^(row&7) applied on the GLOBAL source;
// 2 barriers per 32 MFMAs/wave, reg-prefetch distance 1.
// XCD decode: each XCD owns ONE B-panel (nb = xcd) -> B stays L2-resident.
//  MODE 0 (q-proj, grid 512):  nb = xcd>>1 (4 panels / 8 XCDs)
//  MODE 1 (kv,     grid 768):  nb = xcd (8 panels)
//  MODE 2 (out,    grid 1024): nb = xcd (8 panels)
// ---------------------------------------------------------------------------
template<int MODE>
__global__ __launch_bounds__(256) void gemm_bf16(
    const u16* __restrict__ A, i64 a_bs,
    const u16* __restrict__ Bm,
    float* __restrict__ C, const float* __restrict__ bias,
    u16* __restrict__ x0, u16* __restrict__ x1,
    int Krow, int KT, int M_valid)
{
    __shared__ __align__(16) u16 As[4096], Bs[8192];   // 64 / 128 rows x 64 k
    const int tid = threadIdx.x, lane = tid & 63, w = tid >> 6;
    const int fr = lane & 15, g = lane >> 4;

    // grid decode: ONE B-panel per XCD; mb/bz walk within the XCD
    const int fid = blockIdx.x;
    const int xcd = fid & 7, s = fid >> 3;
    int nb, mb, bz;
    if (MODE == 0)      { nb = xcd >> 1; mb = (xcd & 1) * 64 + s; bz = 0; }   // s 0..63
    else if (MODE == 1) { nb = xcd; mb = s % 24; bz = s / 24; }               // s 0..95
    else                { nb = xcd; mb = s & 31; bz = s >> 5; }               // s 0..127

    // flat staging: per thread 2 A chunks + 4 B chunks (16B each)
    const int srow = tid >> 3, sch = tid & 7;          // 32 rows/round, chunk 0..7
    const int scol = (sch ^ (srow & 7)) << 3;          // pre-swizzled src chunk
    const u16* Asrc = A + (i64)bz * a_bs + ((i64)mb * 64 + srow) * Krow + scol;
    const u16* Bsrc = Bm + ((i64)nb * 128 + srow) * Krow + scol;
    char* Adst = (char*)As + srow * 128 + sch * 16;
    char* Bdst = (char*)Bs + srow * 128 + sch * 16;

    f32x4 acc[2][4];
    #pragma unroll
    for (int i = 0; i < 2; ++i)
        #pragma unroll
        for (int j = 0; j < 4; ++j)
            acc[i][j] = (f32x4){0.f, 0.f, 0.f, 0.f};

    u32x4 st[6];
    st[0] = *(const u32x4*)(Asrc);
    st[1] = *(const u32x4*)(Asrc + (i64)32 * Krow);
    #pragma unroll
    for (int it = 0; it < 4; ++it)
        st[2 + it] = *(const u32x4*)(Bsrc + (i64)(it * 32) * Krow);

    const int wr = (w & 1) * 32, wc = (w >> 1) * 64;   // compute role

    for (int kt = 0; kt < KT; ++kt) {
        __syncthreads();
        *(u32x4*)(Adst) = st[0];
        *(u32x4*)(Adst + 32 * 128) = st[1];
        #pragma unroll
        for (int it = 0; it < 4; ++it)
            *(u32x4*)(Bdst + it * 32 * 128) = st[2 + it];
        __syncthreads();
        if (kt + 1 < KT) {
            st[0] = *(const u32x4*)(Asrc + (kt + 1) * 64);
            st[1] = *(const u32x4*)(Asrc + (i64)32 * Krow + (kt + 1) * 64);
            #pragma unroll
            for (int it = 0; it < 4; ++it)
                st[2 + it] = *(const u32x4*)(Bsrc + (i64)(it * 32) * Krow
                                                  + (kt + 1) * 64);
        }
        #pragma unroll
        for (int half = 0; half < 2; ++half) {
            bf16x8 ah[2], bh[4];
            #pragma unroll
            for (int mi = 0; mi < 2; ++mi) {
                int rr = wr + mi * 16 + fr;
                ah[mi] = *(const bf16x8*)((const char*)As + rr * 128
                                          + (((half * 4 + g) ^ (rr & 7)) << 4));
            }
            #pragma unroll
            for (int ni = 0; ni < 4; ++ni) {
                int rr = wc + ni * 16 + fr;
                bh[ni] = *(const bf16x8*)((const char*)Bs + rr * 128
                                          + (((half * 4 + g) ^ (rr & 7)) << 4));
            }
            #pragma unroll
            for (int mi = 0; mi < 2; ++mi)
                #pragma unroll
                for (int ni = 0; ni < 4; ++ni)
                    acc[mi][ni] = __builtin_amdgcn_mfma_f32_16x16x32_bf16(
                        ah[mi], bh[ni], acc[mi][ni], 0, 0, 0);
        }
    }

    #pragma unroll
    for (int mi = 0; mi < 2; ++mi)
        #pragma unroll
        for (int ni = 0; ni < 4; ++ni) {
            int gm0 = mb * 64 + wr + mi * 16 + g * 4;
            int gn  = nb * 128 + wc + ni * 16 + fr;
            #pragma unroll
            for (int r = 0; r < 4; ++r) {
                int gm = gm0 + r;
                float val = acc[mi][ni][r];
                if (MODE == 0) {
                    x0[(i64)gm * 512 + gn] = f2b(val + bias[gn]);
                } else if (MODE == 1) {
                    if (gm < 1024) {   // v: channel = e*16+h, sigma2 p-slot
                        int e = gm >> 4, hh = gm & 15;
                        i64 so = ((i64)(bz * 16 + hh) * 64 + e) * 1024
                               + (gn & ~31) + (((gn >> 2) & 3) << 3)
                               + (gn & 3) + (((gn >> 4) & 1) << 2);
                        x1[so] = f2b(val);
                    } else {           // k: channel-1024 = d*16+h
                        int c2 = gm - 1024, d = c2 >> 4, hh = c2 & 15;
                        x0[((i64)(bz * 16 + hh) * 1024 + gn) * 32 + d] = f2b(val);
                    }
                } else {
                    if (gm < M_valid)
                        C[(i64)bz * 1024 + (i64)gm * 4096 + gn] = val + bias[gn];
                }
            }
        }
}

// ---------------------------------------------------------------------------
// MFMA attention v10: swapped-QK (P in registers), staged K+V with
// CONFLICT-FREE staging: LINEAR LDS writes (lane tid -> byte tid*16) and the
// XOR swizzle applied on the per-lane GLOBAL source (rule #21 both-sides);
// reads use the same involution -> 2-way (free). Fully unrolled t-loop so
// every staging address is base + immediate. One barrier/iter, XCD-affine.
//  K tile: [64 rows][4 chunks] 64B rows; xor = (row>>1)&3.
//  V tile: [64 rows][8 chunks] 128B rows; xor = row&7.
// ---------------------------------------------------------------------------
__global__ __launch_bounds__(256) void attn_mfma(
    const u16* __restrict__ qu, const u16* __restrict__ kT,
    const u16* __restrict__ vT, u16* __restrict__ attA)
{
    const int g0 = blockIdx.x;
    const int xcd = g0 & 7, sub = g0 >> 3;
    const int lblk = sub & 15;                  // same bh for 16 consecutive
    const int bh = xcd + ((sub >> 4) << 3);     // 8 bh per XCD
    const int b = bh >> 4, h = bh & 15;
    const int tid = threadIdx.x, lane = tid & 63, w = tid >> 6;   // 0..3
    const int fr = lane & 15, g = lane >> 4;
    const int l0 = lblk * 128 + w * 32;

    __shared__ __align__(16) u16 kbuf[2][2048];    // 4 KB per buf, linear 64B rows
    __shared__ __align__(16) u16 vbuf[2][4096];    // 8 KB per buf, linear 128B rows

    // Q fragments (B operand): n = l = fr within tile mf, d-slots g*8..
    bf16x8 aq[2];
    #pragma unroll
    for (int mf = 0; mf < 2; ++mf)
        aq[mf] = *(const bf16x8*)(qu + ((i64)((l0 + mf * 16 + fr) * 4 + b) * 512
                                        + h * 32 + g * 8));   // row = l*4+b

    const f32x4 zf = {0.f, 0.f, 0.f, 0.f};

    // K staging: lane writes LDS byte tid*16 (row sr=tid>>2, slot sc=tid&3);
    // source chunk pre-swizzled sc ^ ((sr>>1)&3).
    const int sr = tid >> 2, sc = tid & 3;
    const u16* ksrc = kT + (i64)bh * 32768 + sr * 32
                    + ((sc ^ ((sr >> 1) & 3)) << 3);           // + t*2048
    char* kdst = (char*)&kbuf[0][0] + tid * 16;                // + buf*4096
    // V staging: lane writes rows vr and vr+32 at slot vs;
    // source chunk pre-swizzled vs ^ (vr&7)  ((vr+32)&7 == vr&7).
    const int vr = tid >> 3, vs = tid & 7;
    const u16* vsrc = vT + (i64)bh * 65536 + (i64)vr * 1024
                    + ((vs ^ (vr & 7)) << 3);                  // + t*64
    char* vdst = (char*)&vbuf[0][0] + tid * 16;                // + buf*8192, +4096

    // prologue: stage tile 0 into buffer 0
    *(u32x4*)kdst = *(const u32x4*)ksrc;
    *(u32x4*)vdst = *(const u32x4*)vsrc;
    *(u32x4*)(vdst + 4096) = *(const u32x4*)(vsrc + 32 * 1024);
    __syncthreads();

    float l_part[2] = {0.f, 0.f};
    f32x4 o[2][4];
    #pragma unroll
    for (int mf = 0; mf < 2; ++mf)
        #pragma unroll
        for (int nf = 0; nf < 4; ++nf)
            o[mf][nf] = zf;

    // hoisted read-swizzle constants (row-dependence reduces to fr bits)
    const int kxor = (fr >> 1) & 3;     // K chunk xor for row nf*16+fr
    const int vxor = fr & 7;            // V slot xor for row nf*16+fr

    #pragma unroll
    for (int t = 0; t < 16; ++t) {
        const int cur = t & 1;
        const int tn = (t < 15) ? t + 1 : 15;

        // 1. issue next-tile global loads (consumed by ds_write below)
        u32x4 knx  = *(const u32x4*)(ksrc + tn * 2048);
        u32x4 vnx0 = *(const u32x4*)(vsrc + tn * 64);
        u32x4 vnx1 = *(const u32x4*)(vsrc + 32 * 1024 + tn * 64);

        // 2. QK(t) from LDS K, swapped operands: T[mf][nf] rows=p, cols=l
        const char* kc_ = (const char*)&kbuf[cur][0];
        f32x4 s[2][4];
        __builtin_amdgcn_s_setprio(1);
        #pragma unroll
        for (int nf = 0; nf < 4; ++nf) {
            int row = nf * 16 + fr;
            bf16x8 ak = *(const bf16x8*)(kc_ + row * 64 + ((g ^ kxor) << 4));
            s[0][nf] = __builtin_amdgcn_mfma_f32_16x16x32_bf16(ak, aq[0], zf, 0, 0, 0);
            s[1][nf] = __builtin_amdgcn_mfma_f32_16x16x32_bf16(ak, aq[1], zf, 0, 0, 0);
        }
        __builtin_amdgcn_s_setprio(0);

        // 3. scale + exp2 + pack straight into PV A-fragment words
        u32x4 ppk[2][2];
        #pragma unroll
        for (int mf = 0; mf < 2; ++mf)
            #pragma unroll
            for (int nf = 0; nf < 4; ++nf) {
                float p_[4];
                #pragma unroll
                for (int r = 0; r < 4; ++r) p_[r] = EXP2(QSCALE * s[mf][nf][r]);
                l_part[mf] += (p_[0] + p_[1]) + (p_[2] + p_[3]);
                ppk[mf][nf >> 1][(nf & 1) * 2 + 0] = cvt_pk_bf16(p_[0], p_[1]);
                ppk[mf][nf >> 1][(nf & 1) * 2 + 1] = cvt_pk_bf16(p_[2], p_[3]);
            }

        // 4. write staged tile t+1 into the other buffers (linear, no conflict)
        {
            const int nb_ = cur ^ 1;
            *(u32x4*)(kdst + nb_ * 4096) = knx;
            *(u32x4*)(vdst + nb_ * 8192) = vnx0;
            *(u32x4*)(vdst + nb_ * 8192 + 4096) = vnx1;
        }

        // 5. PV(t): A = packed P (m = l = fr), B = V fragment from LDS (n = e)
        const char* vc_ = (const char*)&vbuf[cur][0];
        __builtin_amdgcn_s_setprio(1);
        #pragma unroll
        for (int ks = 0; ks < 2; ++ks) {
            bf16x8 ap0 = __builtin_bit_cast(bf16x8, ppk[0][ks]);
            bf16x8 ap1 = __builtin_bit_cast(bf16x8, ppk[1][ks]);
            const int slot = ((ks << 2) | g) ^ vxor;
            #pragma unroll
            for (int nf = 0; nf < 4; ++nf) {
                int row = nf * 16 + fr;
                bf16x8 bv = *(const bf16x8*)(vc_ + row * 128 + (slot << 4));
                o[0][nf] = __builtin_amdgcn_mfma_f32_16x16x32_bf16(ap0, bv, o[0][nf], 0, 0, 0);
                o[1][nf] = __builtin_amdgcn_mfma_f32_16x16x32_bf16(ap1, bv, o[1][nf], 0, 0, 0);
            }
        }
        __builtin_amdgcn_s_setprio(0);

        __syncthreads();   // buf[cur] reads done; buf[cur^1] writes visible
    }

    // row-sum totals: lane holds l_part for l = mf*16 + fr; reduce over g
    #pragma unroll
    for (int mf = 0; mf < 2; ++mf) {
        l_part[mf] += __shfl_xor(l_part[mf], 16);
        l_part[mf] += __shfl_xor(l_part[mf], 32);
    }
    // output: o rows l = mf*16 + 4g + r, cols e = nf*16 + fr
    #pragma unroll
    for (int mf = 0; mf < 2; ++mf)
        #pragma unroll
        for (int r = 0; r < 4; ++r) {
            int l = l0 + mf * 16 + g * 4 + r;
            float tot = __shfl(l_part[mf], g * 4 + r);   // lane fr = 4g+r has it
            if (l < 2046) {
                float inv = 1.f / tot;
                #pragma unroll
                for (int nf = 0; nf < 4; ++nf)
                    attA[((i64)b * 2048 + l) * 1024 + h * 64 + nf * 16 + fr]
                        = f2b(o[mf][nf][r] * inv);
            }
        }
}

// ---------------------------------------------------------------------------
// launch
// ---------------------------------------------------------------------------
extern "C" void kernel_launch(void* const* d_in, const int* in_sizes, int n_in,
                              void* d_out, int out_size, void* d_ws, size_t ws_size,
                              hipStream_t stream) {
    const float* input = (const float*)d_in[0];  // [2046][4][1024]
    const float* w_kv  = (const float*)d_in[1];  // [1024][2048]
    const float* w_q   = (const float*)d_in[2];  // [512][1024]
    const float* b_q   = (const float*)d_in[3];  // [512]
    const float* w_out = (const float*)d_in[4];  // [1024][1024]
    const float* b_out = (const float*)d_in[5];  // [1024]
    float* out = (float*)d_out;                  // [2046][4][1024]

    char* W = (char*)d_ws;
    u16* Xb      = (u16*)(W + 16777216);     // 8192x1024      (16 MB)
    u16* qu      = (u16*)(W + 33554432);     // 8192x512       (8 MB) unscaled
    u16* wq_b    = (u16*)(W + 41943040);     // 512x1024       (1 MB)
    u16* wkv_b   = (u16*)(W + 42991616);     // 1024x2048      (4 MB)
    u16* wout_b  = (u16*)(W + 47185920);     // 1024x1024      (2 MB)
    u16* kvA     = (u16*)(W + 49283072);     // 4x1536x2048    (24 MB)
    u16* kT      = (u16*)(W + 74448896);     // 4x16x1024x32   (4 MB)
    u16* vT      = (u16*)(W + 78643200);     // 4x16x64x1024   (8 MB)
    u16* attA    = (u16*)(W + 87031808);     // 4x2048x1024    (16 MB)

    dim3 blk(256);

    // all bf16 conversions in ONE dispatch
    conv_all<<<dim3(11776), blk, 0, stream>>>(
        input, w_q, w_kv, w_out, Xb, wq_b, wkv_b, wout_b);

    // q' = X @ w_q^T + b_q -> qu bf16 (unscaled)
    gemm_bf16<0><<<dim3(512), blk, 0, stream>>>(
        Xb, 0, wq_b, nullptr, b_q, qu, nullptr, 1024, 16, 8192);

    // combined kv A-panel (Xb + qu, transposed bf16)
    build_kvA<<<dim3(32, 24, 4), blk, 0, stream>>>(Xb, qu, kvA);

    // [v;k] = kvA @ wkv_b^T -> kT/vT bf16 (per b; vT in sigma2 layout)
    gemm_bf16<1><<<dim3(768), blk, 0, stream>>>(
        kvA, (i64)1536 * 2048, wkv_b, nullptr, nullptr, kT, vT, 2048, 32, 1536);

    // attention -> attA bf16 (swapped-QK, P-in-register, conflict-free staging)
    attn_mfma<<<dim3(1024), blk, 0, stream>>>(qu, kT, vT, attA);

    // out = attA @ wout_b^T + b_out (per b)
    gemm_bf16<2><<<dim3(1024), blk, 0, stream>>>(
        attA, (i64)2048 * 1024, wout_b, out, b_out, nullptr, nullptr, 1024, 16, 2046);
}